// Round 2
// baseline (11661.983 us; speedup 1.0000x reference)
//
#include <hip/hip_runtime.h>

typedef unsigned short u16;
typedef unsigned int   u32;
typedef __attribute__((ext_vector_type(8))) short  short8;
typedef __attribute__((ext_vector_type(4))) float  f32x4;

#define D_     2048
#define S_     512
#define B_     2
#define FFN_   8192
#define INNER_ 512
#define NROW   1024          // B_*S_
#define NBLK_SCAN 128
#define NGRP   16
#define GRPSZ  8             // NBLK_SCAN / NGRP

// ---------------- device globals (scratch + transposed bf16 weights) ----------------
__device__ u16 g_WqT[D_*D_], g_WkT[D_*D_], g_WvT[D_*D_], g_WzT[D_*D_];
__device__ u16 g_WgT[D_*D_], g_WmhT[D_*D_], g_WmiT[D_*D_], g_WoT[D_*D_];
__device__ u16 g_Wd1T[INNER_*D_], g_Wd2T[D_*INNER_];
__device__ u16 g_W1fT[FFN_*D_], g_W2fT[D_*FFN_];
__device__ u16 g_xn[NROW*D_], g_q[NROW*D_], g_k[NROW*D_], g_v[NROW*D_], g_z[NROW*D_];
__device__ u16 g_t1[NROW*INNER_];
__device__ float g_gamma[NROW*D_], g_zWmi[NROW*D_], g_H[NROW*D_];
__device__ float g_memctx[NROW*D_], g_xres[NROW*D_];
__device__ u16 g_ctx[NROW*D_], g_xrn[NROW*D_], g_ffn1[NROW*FFN_];
__device__ u32 g_cnt[NGRP];
__device__ u32 g_root;
__device__ u32 g_gen;

// ---------------- helpers ----------------
__device__ __forceinline__ float b2f(u16 u) {
  union { u32 i; float f; } c; c.i = ((u32)u) << 16; return c.f;
}
__device__ __forceinline__ u16 f2b(float f) {
  union { float f; u32 i; } c; c.f = f;
  u32 u = c.i;
  return (u16)((u + 0x7fffu + ((u >> 16) & 1u)) >> 16);
}

// ---------------- transpose+cast: in f32 [K][N] -> out bf16 [N][K] ----------------
__global__ __launch_bounds__(256) void transpose_k(const float* __restrict__ in,
                                                   u16* __restrict__ out,
                                                   int K, int N) {
  __shared__ u16 tl[64][72];
  int kb = blockIdx.x * 64, nb = blockIdx.y * 64;
  {
    int rh = threadIdx.x >> 4;        // 0..15
    int c4 = (threadIdx.x & 15) * 4;  // 0..60
#pragma unroll
    for (int rr = 0; rr < 64; rr += 16) {
      int r = rr + rh;
      float4 v4 = *(const float4*)&in[(size_t)(kb + r) * N + nb + c4];
      tl[r][c4]     = f2b(v4.x);
      tl[r][c4 + 1] = f2b(v4.y);
      tl[r][c4 + 2] = f2b(v4.z);
      tl[r][c4 + 3] = f2b(v4.w);
    }
  }
  __syncthreads();
  {
    int rh = threadIdx.x >> 3;        // 0..31
    int c8 = (threadIdx.x & 7) * 8;   // 0..56
#pragma unroll
    for (int rr = 0; rr < 64; rr += 32) {
      int n = rr + rh;
      u16 tmp[8];
#pragma unroll
      for (int i = 0; i < 8; ++i) tmp[i] = tl[c8 + i][n];
      *(uint4*)&out[(size_t)(nb + n) * K + kb + c8] = *(const uint4*)tmp;
    }
  }
}

// ---------------- rmsnorm: f32 in, f32 weight, bf16 out ----------------
__global__ __launch_bounds__(256) void rmsnorm_k(const float* __restrict__ x,
                                                 const float* __restrict__ w,
                                                 u16* __restrict__ out) {
  __shared__ float red[4];
  int row = blockIdx.x;
  const float* xr = x + (size_t)row * D_;
  int base = threadIdx.x * 8;
  float4 a = *(const float4*)&xr[base];
  float4 b = *(const float4*)&xr[base + 4];
  float xs[8] = {a.x, a.y, a.z, a.w, b.x, b.y, b.z, b.w};
  float s = 0.f;
#pragma unroll
  for (int i = 0; i < 8; ++i) s += xs[i] * xs[i];
  for (int off = 32; off >= 1; off >>= 1) s += __shfl_xor(s, off);
  int wave = threadIdx.x >> 6;
  if ((threadIdx.x & 63) == 0) red[wave] = s;
  __syncthreads();
  float tot = red[0] + red[1] + red[2] + red[3];
  float sc = 1.f / (sqrtf(tot * (1.f / (float)D_)) + 1e-6f);
  float4 wa = *(const float4*)&w[base];
  float4 wb = *(const float4*)&w[base + 4];
  float ws[8] = {wa.x, wa.y, wa.z, wa.w, wb.x, wb.y, wb.z, wb.w};
  u32 po[4];
#pragma unroll
  for (int i = 0; i < 4; ++i)
    po[i] = (u32)f2b(xs[2*i] * sc * ws[2*i]) | ((u32)f2b(xs[2*i+1] * sc * ws[2*i+1]) << 16);
  *(uint4*)&out[(size_t)row * D_ + base] = *(const uint4*)po;
}

// ---------------- MFMA GEMM: C[M,N] = act(A[M,K] @ B + bias); BT = B^T [N][K] bf16 ----------------
// EPI: 0 none->bf16, 1 relu->bf16, 2 sigmoid->f32, 3 gelu->bf16, 4 none->f32, 5 +res->f32
template <int EPI>
__global__ __launch_bounds__(256, 2)
void gemm_bt(const u16* __restrict__ A, const u16* __restrict__ BT,
             const float* __restrict__ bias, const float* __restrict__ res,
             void* __restrict__ outp, int M, int N, int K) {
  __shared__ u16 As[128 * 40];  // [row][k], pad to 40
  __shared__ u16 Bs[128 * 40];  // [col][k]
  const int tid = threadIdx.x;
  const int wave = tid >> 6, lane = tid & 63;
  const int m0 = blockIdx.x * 128, n0 = blockIdx.y * 128;
  const int ar = tid >> 2;
  const int ac = (tid & 3) * 8;
  const u16* Ag = A + (size_t)(m0 + ar) * K + ac;
  const u16* Bg = BT + (size_t)(n0 + ar) * K + ac;
  uint4 pa0 = *(const uint4*)Ag;
  uint4 pa1 = *(const uint4*)(Ag + (size_t)64 * K);
  uint4 pb0 = *(const uint4*)Bg;
  uint4 pb1 = *(const uint4*)(Bg + (size_t)64 * K);
  const int wm = (wave >> 1) * 64, wn = (wave & 1) * 64;
  const int q = lane >> 4, mr = lane & 15;
  const int q8 = q * 8;
  f32x4 acc[4][4];
#pragma unroll
  for (int mi = 0; mi < 4; ++mi)
#pragma unroll
    for (int ni = 0; ni < 4; ++ni) { acc[mi][ni][0]=0.f; acc[mi][ni][1]=0.f; acc[mi][ni][2]=0.f; acc[mi][ni][3]=0.f; }

  for (int k0 = 0; k0 < K; k0 += 32) {
    __syncthreads();
    *(uint4*)&As[ar * 40 + ac] = pa0;
    *(uint4*)&As[(ar + 64) * 40 + ac] = pa1;
    *(uint4*)&Bs[ar * 40 + ac] = pb0;
    *(uint4*)&Bs[(ar + 64) * 40 + ac] = pb1;
    __syncthreads();
    if (k0 + 32 < K) {
      pa0 = *(const uint4*)(Ag + k0 + 32);
      pa1 = *(const uint4*)(Ag + (size_t)64 * K + k0 + 32);
      pb0 = *(const uint4*)(Bg + k0 + 32);
      pb1 = *(const uint4*)(Bg + (size_t)64 * K + k0 + 32);
    }
    short8 af[4], bv[4];
#pragma unroll
    for (int mi = 0; mi < 4; ++mi) af[mi] = *(const short8*)&As[(wm + mi * 16 + mr) * 40 + q8];
#pragma unroll
    for (int ni = 0; ni < 4; ++ni) bv[ni] = *(const short8*)&Bs[(wn + ni * 16 + mr) * 40 + q8];
#pragma unroll
    for (int mi = 0; mi < 4; ++mi)
#pragma unroll
      for (int ni = 0; ni < 4; ++ni)
        acc[mi][ni] = __builtin_amdgcn_mfma_f32_16x16x32_bf16(af[mi], bv[ni], acc[mi][ni], 0, 0, 0);
  }
  // epilogue: C/D layout col=lane&15, row=q*4+r
  float* outf = (float*)outp;
  u16* outh = (u16*)outp;
#pragma unroll
  for (int mi = 0; mi < 4; ++mi)
#pragma unroll
    for (int r = 0; r < 4; ++r) {
      int row = m0 + wm + mi * 16 + q * 4 + r;
#pragma unroll
      for (int ni = 0; ni < 4; ++ni) {
        int col = n0 + wn + ni * 16 + mr;
        float v = acc[mi][ni][r];
        if (bias) v += bias[col];
        if (EPI == 1) v = fmaxf(v, 0.f);
        if (EPI == 2) v = 1.f / (1.f + __expf(-v));
        if (EPI == 3) v = 0.5f * v * (1.f + erff(v * 0.70710678118654752f));
        if (EPI == 5) v += res[(size_t)row * N + col];
        if (EPI == 2 || EPI == 4 || EPI == 5) outf[(size_t)row * N + col] = v;
        else                                  outh[(size_t)row * N + col] = f2b(v);
      }
    }
}

// ---------------- grid barrier (agent-scope, 2-level) ----------------
__device__ __forceinline__ void grid_barrier() {
  __syncthreads();
  if (threadIdx.x == 0) {
    __threadfence();  // make this block's stores device-visible
    u32 g0 = __hip_atomic_load(&g_gen, __ATOMIC_RELAXED, __HIP_MEMORY_SCOPE_AGENT);
    int grp = blockIdx.x & (NGRP - 1);
    u32 n = __hip_atomic_fetch_add(&g_cnt[grp], 1u, __ATOMIC_ACQ_REL, __HIP_MEMORY_SCOPE_AGENT);
    bool done = false;
    if (n == GRPSZ - 1) {
      u32 r = __hip_atomic_fetch_add(&g_root, 1u, __ATOMIC_ACQ_REL, __HIP_MEMORY_SCOPE_AGENT);
      if (r == NGRP - 1) {
        for (int i = 0; i < NGRP; ++i)
          __hip_atomic_store(&g_cnt[i], 0u, __ATOMIC_RELAXED, __HIP_MEMORY_SCOPE_AGENT);
        __hip_atomic_store(&g_root, 0u, __ATOMIC_RELAXED, __HIP_MEMORY_SCOPE_AGENT);
        __hip_atomic_fetch_add(&g_gen, 1u, __ATOMIC_RELEASE, __HIP_MEMORY_SCOPE_AGENT);
        done = true;
      }
    }
    if (!done) {
      while (__hip_atomic_load(&g_gen, __ATOMIC_ACQUIRE, __HIP_MEMORY_SCOPE_AGENT) == g0)
        __builtin_amdgcn_s_sleep(2);
    }
    __threadfence();  // invalidate stale lines before re-reading Hst
  }
  __syncthreads();
}

// ---------------- persistent scan: h_t = z*sig(Wg h)+gamma*h+0.1*tanh(zWmi+Wmh h) ----------------
__global__ __launch_bounds__(256, 1)
void scan_kernel(const u16* __restrict__ WgT, const u16* __restrict__ WmhT,
                 const u16* __restrict__ zb, const float* __restrict__ gammab,
                 const float* __restrict__ zWmib, const float* __restrict__ bg,
                 const float* __restrict__ bm, float* __restrict__ Hst) {
  __shared__ float hl[2 * D_];        // h_prev, fp32
  __shared__ float dotbuf[32][2];     // [mat*16+jj][b]
  const int tid = threadIdx.x, wave = tid >> 6, lane = tid & 63;
  const int j0 = blockIdx.x * 16;

  // weights in registers: wave w owns cols cc = w*8..w*8+7 (cc<16 -> Wg col j0+cc, else Wmh)
  u32 w_reg[8][16];
#pragma unroll
  for (int c = 0; c < 8; ++c) {
    int cc = wave * 8 + c;
    const u16* Wt = (cc < 16 ? WgT : WmhT) + (size_t)(j0 + (cc & 15)) * D_;
#pragma unroll
    for (int i = 0; i < 16; ++i)
      w_reg[c][i] = *(const u32*)&Wt[i * 128 + lane * 2];
  }
  for (int i = tid; i < 2 * D_; i += 256) hl[i] = 0.f;
  __syncthreads();

  for (int t = 0; t < S_; ++t) {
    float acc[8][2];
#pragma unroll
    for (int c = 0; c < 8; ++c) { acc[c][0] = 0.f; acc[c][1] = 0.f; }
#pragma unroll
    for (int b2 = 0; b2 < 2; ++b2) {
      const float2* hp2 = (const float2*)&hl[b2 * D_];
#pragma unroll
      for (int i = 0; i < 16; ++i) {
        float2 h2 = hp2[i * 64 + lane];
#pragma unroll
        for (int c = 0; c < 8; ++c) {
          u32 w = w_reg[c][i];
          float w0 = b2f((u16)(w & 0xffff));
          float w1 = b2f((u16)(w >> 16));
          acc[c][b2] += w0 * h2.x + w1 * h2.y;
        }
      }
    }
#pragma unroll
    for (int c = 0; c < 8; ++c)
#pragma unroll
      for (int b2 = 0; b2 < 2; ++b2) {
        float v = acc[c][b2];
        for (int off = 32; off >= 1; off >>= 1) v += __shfl_xor(v, off);
        if (lane == 0) dotbuf[wave * 8 + c][b2] = v;
      }
    __syncthreads();
    if (tid < 32) {
      int jj = tid & 15, b = tid >> 4;
      int j = j0 + jj;
      size_t off = ((size_t)b * S_ + t) * D_ + j;
      float gd = dotbuf[jj][b] + bg[j];
      float md = dotbuf[16 + jj][b] + bm[j];
      float gate = 1.f / (1.f + __expf(-gd));
      float hnew = tanhf(zWmib[off] + md);
      float hv = b2f(zb[off]) * gate + gammab[off] * hl[b * D_ + j] + 0.1f * hnew;
      Hst[off] = hv;
    }
    grid_barrier();
    {
      int i4 = tid * 16;
      int b = i4 >> 11, kk = i4 & (D_ - 1);
      const float* src = &Hst[((size_t)b * S_ + t) * D_ + kk];
      float4* dst = (float4*)&hl[i4];
#pragma unroll
      for (int u = 0; u < 4; ++u) dst[u] = *(const float4*)&src[u * 4];
    }
    __syncthreads();
  }
}

// ---------------- slot attention over bank (parallel over all t) ----------------
__global__ __launch_bounds__(256)
void attn_kernel(const u16* __restrict__ Q, const float* __restrict__ Hst,
                 u16* __restrict__ CTX) {
  __shared__ float qs[4][128];
  const int wave = threadIdx.x >> 6, lane = threadIdx.x & 63;
  const int task = blockIdx.x * 4 + wave;         // 16384 tasks
  const int h = task & 15;
  const int t = (task >> 4) & (S_ - 1);
  const int b = task >> 13;
  const int row = b * S_ + t;
  {
    u32 qv = *(const u32*)&Q[(size_t)row * D_ + h * 128 + lane * 2];
    qs[wave][lane * 2]     = b2f((u16)(qv & 0xffff));
    qs[wave][lane * 2 + 1] = b2f((u16)(qv >> 16));
  }
  __syncthreads();
  const int s = lane & 31, half = lane >> 5;
  int j = t - 1 - s;                 // the 32 most recent states; slot id = j%32 (unique)
  bool valid = (t > 0) && (j >= 0);
  float dot = 0.f;
  if (valid) {
    const float* Krow = Hst + ((size_t)b * S_ + j) * D_ + h * 128 + half * 64;
    const float* qp = &qs[wave][half * 64];
#pragma unroll
    for (int it = 0; it < 16; ++it) {
      float4 kv = *(const float4*)&Krow[it * 4];
      dot += qp[it*4] * kv.x + qp[it*4+1] * kv.y + qp[it*4+2] * kv.z + qp[it*4+3] * kv.w;
    }
  }
  dot += __shfl_xor(dot, 32);
  float score = valid ? dot * 0.08838834764831843f : 0.f;  // 1/sqrt(128); empty slot -> q.0=0
  float mx = score;
  for (int off = 16; off >= 1; off >>= 1) mx = fmaxf(mx, __shfl_xor(mx, off));
  float p = __expf(score - mx);
  float sum = p;
  for (int off = 16; off >= 1; off >>= 1) sum += __shfl_xor(sum, off);
  float aw = p / sum;
  // ctx: lane covers dims d0 = lane*2, d0+1
  float cx = 0.f, cy = 0.f;
  for (int ss = 0; ss < 32; ++ss) {
    float a = __shfl(aw, ss);
    int jj2 = t - 1 - ss;
    if (t > 0 && jj2 >= 0) {
      float2 kv = *(const float2*)&Hst[((size_t)b * S_ + jj2) * D_ + h * 128 + lane * 2];
      cx += a * kv.x; cy += a * kv.y;
    }
  }
  u32 o = (u32)f2b(cx) | ((u32)f2b(cy) << 16);
  *(u32*)&CTX[(size_t)row * D_ + h * 128 + lane * 2] = o;
}

// ---------------- combine: x_res = x + h + memctx + 0.1*v (f32 out) ----------------
__global__ __launch_bounds__(256)
void combine_k(const float* __restrict__ x, const u16* __restrict__ v,
               const float* __restrict__ Hs, const float* __restrict__ mc,
               float* __restrict__ xres) {
  size_t i = ((size_t)blockIdx.x * 256 + threadIdx.x) * 4;
  float4 xv = *(const float4*)&x[i];
  uint2 vv = *(const uint2*)&v[i];
  float4 hh = *(const float4*)&Hs[i];
  float4 m  = *(const float4*)&mc[i];
  float4 o;
  o.x = xv.x + hh.x + m.x + 0.1f * b2f((u16)(vv.x & 0xffff));
  o.y = xv.y + hh.y + m.y + 0.1f * b2f((u16)(vv.x >> 16));
  o.z = xv.z + hh.z + m.z + 0.1f * b2f((u16)(vv.y & 0xffff));
  o.w = xv.w + hh.w + m.w + 0.1f * b2f((u16)(vv.y >> 16));
  *(float4*)&xres[i] = o;
}

// ---------------- host ----------------
static void* sym(const void* s) { void* p = nullptr; (void)hipGetSymbolAddress(&p, s); return p; }

extern "C" void kernel_launch(void* const* d_in, const int* in_sizes, int n_in,
                              void* d_out, int out_size, void* d_ws, size_t ws_size,
                              hipStream_t stream) {
  (void)in_sizes; (void)n_in; (void)d_ws; (void)ws_size; (void)out_size;
  const float* x   = (const float*)d_in[0];
  const float* Wq  = (const float*)d_in[1];  const float* bq  = (const float*)d_in[2];
  const float* Wk  = (const float*)d_in[3];  const float* bk  = (const float*)d_in[4];
  const float* Wv  = (const float*)d_in[5];  const float* bv  = (const float*)d_in[6];
  const float* Wz  = (const float*)d_in[7];  const float* bz  = (const float*)d_in[8];
  const float* Wg  = (const float*)d_in[9];  const float* bg  = (const float*)d_in[10];
  const float* n1w = (const float*)d_in[11]; const float* n2w = (const float*)d_in[12];
  const float* Wd1 = (const float*)d_in[13]; const float* bd1 = (const float*)d_in[14];
  const float* Wd2 = (const float*)d_in[15]; const float* bd2 = (const float*)d_in[16];
  const float* Wmi = (const float*)d_in[17];
  const float* Wmh = (const float*)d_in[18]; const float* bm  = (const float*)d_in[19];
  const float* Wo  = (const float*)d_in[20]; const float* bo  = (const float*)d_in[21];
  const float* W1f = (const float*)d_in[22]; const float* b1f = (const float*)d_in[23];
  const float* W2f = (const float*)d_in[24]; const float* b2f_ = (const float*)d_in[25];

  u16* WqT  = (u16*)sym(HIP_SYMBOL(g_WqT));   u16* WkT  = (u16*)sym(HIP_SYMBOL(g_WkT));
  u16* WvT  = (u16*)sym(HIP_SYMBOL(g_WvT));   u16* WzT  = (u16*)sym(HIP_SYMBOL(g_WzT));
  u16* WgT  = (u16*)sym(HIP_SYMBOL(g_WgT));   u16* WmhT = (u16*)sym(HIP_SYMBOL(g_WmhT));
  u16* WmiT = (u16*)sym(HIP_SYMBOL(g_WmiT));  u16* WoT  = (u16*)sym(HIP_SYMBOL(g_WoT));
  u16* Wd1T = (u16*)sym(HIP_SYMBOL(g_Wd1T));  u16* Wd2T = (u16*)sym(HIP_SYMBOL(g_Wd2T));
  u16* W1fT = (u16*)sym(HIP_SYMBOL(g_W1fT));  u16* W2fT = (u16*)sym(HIP_SYMBOL(g_W2fT));
  u16* xn  = (u16*)sym(HIP_SYMBOL(g_xn));
  u16* qb  = (u16*)sym(HIP_SYMBOL(g_q));   u16* kb2 = (u16*)sym(HIP_SYMBOL(g_k));
  u16* vb  = (u16*)sym(HIP_SYMBOL(g_v));   u16* zb  = (u16*)sym(HIP_SYMBOL(g_z));
  u16* t1  = (u16*)sym(HIP_SYMBOL(g_t1));
  float* gamma  = (float*)sym(HIP_SYMBOL(g_gamma));
  float* zWmi   = (float*)sym(HIP_SYMBOL(g_zWmi));
  float* Hst    = (float*)sym(HIP_SYMBOL(g_H));
  float* memctx = (float*)sym(HIP_SYMBOL(g_memctx));
  float* xres   = (float*)sym(HIP_SYMBOL(g_xres));
  u16* ctx  = (u16*)sym(HIP_SYMBOL(g_ctx));
  u16* xrn  = (u16*)sym(HIP_SYMBOL(g_xrn));
  u16* ffn1 = (u16*)sym(HIP_SYMBOL(g_ffn1));

  // weight transposes + fp32->bf16 casts (every launch; idempotent)
  transpose_k<<<dim3(32, 32), 256, 0, stream>>>(Wq,  WqT,  D_, D_);
  transpose_k<<<dim3(32, 32), 256, 0, stream>>>(Wk,  WkT,  D_, D_);
  transpose_k<<<dim3(32, 32), 256, 0, stream>>>(Wv,  WvT,  D_, D_);
  transpose_k<<<dim3(32, 32), 256, 0, stream>>>(Wz,  WzT,  D_, D_);
  transpose_k<<<dim3(32, 32), 256, 0, stream>>>(Wg,  WgT,  D_, D_);
  transpose_k<<<dim3(32, 32), 256, 0, stream>>>(Wmh, WmhT, D_, D_);
  transpose_k<<<dim3(32, 32), 256, 0, stream>>>(Wmi, WmiT, D_, D_);
  transpose_k<<<dim3(32, 32), 256, 0, stream>>>(Wo,  WoT,  D_, D_);
  transpose_k<<<dim3(32, 8),  256, 0, stream>>>(Wd1, Wd1T, D_, INNER_);
  transpose_k<<<dim3(8, 32),  256, 0, stream>>>(Wd2, Wd2T, INNER_, D_);
  transpose_k<<<dim3(32, 128), 256, 0, stream>>>(W1f, W1fT, D_, FFN_);
  transpose_k<<<dim3(128, 32), 256, 0, stream>>>(W2f, W2fT, FFN_, D_);

  rmsnorm_k<<<NROW, 256, 0, stream>>>(x, n1w, xn);

  gemm_bt<0><<<dim3(8, 16), 256, 0, stream>>>(xn, WqT, bq, nullptr, qb,  NROW, D_, D_);
  gemm_bt<0><<<dim3(8, 16), 256, 0, stream>>>(xn, WkT, bk, nullptr, kb2, NROW, D_, D_);
  gemm_bt<0><<<dim3(8, 16), 256, 0, stream>>>(xn, WvT, bv, nullptr, vb,  NROW, D_, D_);
  gemm_bt<0><<<dim3(8, 16), 256, 0, stream>>>(xn, WzT, bz, nullptr, zb,  NROW, D_, D_);

  gemm_bt<1><<<dim3(8, 4),  256, 0, stream>>>(kb2, Wd1T, bd1, nullptr, t1,    NROW, INNER_, D_);
  gemm_bt<2><<<dim3(8, 16), 256, 0, stream>>>(t1,  Wd2T, bd2, nullptr, gamma, NROW, D_, INNER_);
  gemm_bt<4><<<dim3(8, 16), 256, 0, stream>>>(zb,  WmiT, nullptr, nullptr, zWmi, NROW, D_, D_);

  scan_kernel<<<NBLK_SCAN, 256, 0, stream>>>(WgT, WmhT, zb, gamma, zWmi, bg, bm, Hst);

  attn_kernel<<<4096, 256, 0, stream>>>(qb, Hst, ctx);
  gemm_bt<4><<<dim3(8, 16), 256, 0, stream>>>(ctx, WoT, bo, nullptr, memctx, NROW, D_, D_);
  combine_k<<<2048, 256, 0, stream>>>(x, vb, Hst, memctx, xres);

  rmsnorm_k<<<NROW, 256, 0, stream>>>(xres, n2w, xrn);
  gemm_bt<3><<<dim3(8, 64), 256, 0, stream>>>(xrn,  W1fT, b1f, nullptr, ffn1, NROW, FFN_, D_);
  gemm_bt<5><<<dim3(8, 16), 256, 0, stream>>>(ffn1, W2fT, b2f_, xres, (float*)d_out, NROW, D_, FFN_);
}

// Round 3
// 4423.349 us; speedup vs baseline: 2.6365x; 2.6365x over previous
//
#include <hip/hip_runtime.h>

typedef unsigned short u16;
typedef unsigned int   u32;
typedef __attribute__((ext_vector_type(8))) short  short8;
typedef __attribute__((ext_vector_type(4))) float  f32x4;

#define D_     2048
#define S_     512
#define B_     2
#define FFN_   8192
#define INNER_ 512
#define NROW   1024          // B_*S_
#define SNBLK  256           // scan blocks: 128 col-blocks x 2 batches
#define SNGRP  16
#define SGRPSZ 16            // SNBLK / SNGRP
#define CPAD   32            // one 128B line per counter

// ---------------- device globals (scratch + transposed bf16 weights) ----------------
__device__ u16 g_WqT[D_*D_], g_WkT[D_*D_], g_WvT[D_*D_], g_WzT[D_*D_];
__device__ u16 g_WgT[D_*D_], g_WmhT[D_*D_], g_WmiT[D_*D_], g_WoT[D_*D_];
__device__ u16 g_Wd1T[INNER_*D_], g_Wd2T[D_*INNER_];
__device__ u16 g_W1fT[FFN_*D_], g_W2fT[D_*FFN_];
__device__ u16 g_xn[NROW*D_], g_q[NROW*D_], g_k[NROW*D_], g_v[NROW*D_], g_z[NROW*D_];
__device__ u16 g_t1[NROW*INNER_];
__device__ float g_gamma[NROW*D_], g_zWmi[NROW*D_], g_H[NROW*D_];
__device__ float g_memctx[NROW*D_], g_xres[NROW*D_];
__device__ u16 g_ctx[NROW*D_], g_xrn[NROW*D_], g_ffn1[NROW*FFN_];
__device__ u32 g_cnt[SNGRP * CPAD];
__device__ u32 g_root[CPAD];
__device__ u32 g_gen[CPAD];

// ---------------- helpers ----------------
__device__ __forceinline__ float b2f(u16 u) {
  union { u32 i; float f; } c; c.i = ((u32)u) << 16; return c.f;
}
__device__ __forceinline__ u16 f2b(float f) {
  union { float f; u32 i; } c; c.f = f;
  u32 u = c.i;
  return (u16)((u + 0x7fffu + ((u >> 16) & 1u)) >> 16);
}

// ---------------- transpose+cast: in f32 [K][N] -> out bf16 [N][K] ----------------
__global__ __launch_bounds__(256) void transpose_k(const float* __restrict__ in,
                                                   u16* __restrict__ out,
                                                   int K, int N) {
  __shared__ u16 tl[64][72];
  int kb = blockIdx.x * 64, nb = blockIdx.y * 64;
  {
    int rh = threadIdx.x >> 4;        // 0..15
    int c4 = (threadIdx.x & 15) * 4;  // 0..60
#pragma unroll
    for (int rr = 0; rr < 64; rr += 16) {
      int r = rr + rh;
      float4 v4 = *(const float4*)&in[(size_t)(kb + r) * N + nb + c4];
      tl[r][c4]     = f2b(v4.x);
      tl[r][c4 + 1] = f2b(v4.y);
      tl[r][c4 + 2] = f2b(v4.z);
      tl[r][c4 + 3] = f2b(v4.w);
    }
  }
  __syncthreads();
  {
    int rh = threadIdx.x >> 3;        // 0..31
    int c8 = (threadIdx.x & 7) * 8;   // 0..56
#pragma unroll
    for (int rr = 0; rr < 64; rr += 32) {
      int n = rr + rh;
      u16 tmp[8];
#pragma unroll
      for (int i = 0; i < 8; ++i) tmp[i] = tl[c8 + i][n];
      *(uint4*)&out[(size_t)(nb + n) * K + kb + c8] = *(const uint4*)tmp;
    }
  }
}

// ---------------- rmsnorm: f32 in, f32 weight, bf16 out ----------------
__global__ __launch_bounds__(256) void rmsnorm_k(const float* __restrict__ x,
                                                 const float* __restrict__ w,
                                                 u16* __restrict__ out) {
  __shared__ float red[4];
  int row = blockIdx.x;
  const float* xr = x + (size_t)row * D_;
  int base = threadIdx.x * 8;
  float4 a = *(const float4*)&xr[base];
  float4 b = *(const float4*)&xr[base + 4];
  float xs[8] = {a.x, a.y, a.z, a.w, b.x, b.y, b.z, b.w};
  float s = 0.f;
#pragma unroll
  for (int i = 0; i < 8; ++i) s += xs[i] * xs[i];
  for (int off = 32; off >= 1; off >>= 1) s += __shfl_xor(s, off);
  int wave = threadIdx.x >> 6;
  if ((threadIdx.x & 63) == 0) red[wave] = s;
  __syncthreads();
  float tot = red[0] + red[1] + red[2] + red[3];
  float sc = 1.f / (sqrtf(tot * (1.f / (float)D_)) + 1e-6f);
  float4 wa = *(const float4*)&w[base];
  float4 wb = *(const float4*)&w[base + 4];
  float ws[8] = {wa.x, wa.y, wa.z, wa.w, wb.x, wb.y, wb.z, wb.w};
  u32 po[4];
#pragma unroll
  for (int i = 0; i < 4; ++i)
    po[i] = (u32)f2b(xs[2*i] * sc * ws[2*i]) | ((u32)f2b(xs[2*i+1] * sc * ws[2*i+1]) << 16);
  *(uint4*)&out[(size_t)row * D_ + base] = *(const uint4*)po;
}

// ---------------- MFMA GEMM: C[M,N] = act(A[M,K] @ B + bias); BT = B^T [N][K] bf16 ----------------
// EPI: 0 none->bf16, 1 relu->bf16, 2 sigmoid->f32, 3 gelu->bf16, 4 none->f32, 5 +res->f32
template <int EPI>
__global__ __launch_bounds__(256, 2)
void gemm_bt(const u16* __restrict__ A, const u16* __restrict__ BT,
             const float* __restrict__ bias, const float* __restrict__ res,
             void* __restrict__ outp, int M, int N, int K) {
  __shared__ u16 As[128 * 40];  // [row][k], pad to 40
  __shared__ u16 Bs[128 * 40];  // [col][k]
  const int tid = threadIdx.x;
  const int wave = tid >> 6, lane = tid & 63;
  const int m0 = blockIdx.x * 128, n0 = blockIdx.y * 128;
  const int ar = tid >> 2;
  const int ac = (tid & 3) * 8;
  const u16* Ag = A + (size_t)(m0 + ar) * K + ac;
  const u16* Bg = BT + (size_t)(n0 + ar) * K + ac;
  uint4 pa0 = *(const uint4*)Ag;
  uint4 pa1 = *(const uint4*)(Ag + (size_t)64 * K);
  uint4 pb0 = *(const uint4*)Bg;
  uint4 pb1 = *(const uint4*)(Bg + (size_t)64 * K);
  const int wm = (wave >> 1) * 64, wn = (wave & 1) * 64;
  const int q = lane >> 4, mr = lane & 15;
  const int q8 = q * 8;
  f32x4 acc[4][4];
#pragma unroll
  for (int mi = 0; mi < 4; ++mi)
#pragma unroll
    for (int ni = 0; ni < 4; ++ni) { acc[mi][ni][0]=0.f; acc[mi][ni][1]=0.f; acc[mi][ni][2]=0.f; acc[mi][ni][3]=0.f; }

  for (int k0 = 0; k0 < K; k0 += 32) {
    __syncthreads();
    *(uint4*)&As[ar * 40 + ac] = pa0;
    *(uint4*)&As[(ar + 64) * 40 + ac] = pa1;
    *(uint4*)&Bs[ar * 40 + ac] = pb0;
    *(uint4*)&Bs[(ar + 64) * 40 + ac] = pb1;
    __syncthreads();
    if (k0 + 32 < K) {
      pa0 = *(const uint4*)(Ag + k0 + 32);
      pa1 = *(const uint4*)(Ag + (size_t)64 * K + k0 + 32);
      pb0 = *(const uint4*)(Bg + k0 + 32);
      pb1 = *(const uint4*)(Bg + (size_t)64 * K + k0 + 32);
    }
    short8 af[4], bv[4];
#pragma unroll
    for (int mi = 0; mi < 4; ++mi) af[mi] = *(const short8*)&As[(wm + mi * 16 + mr) * 40 + q8];
#pragma unroll
    for (int ni = 0; ni < 4; ++ni) bv[ni] = *(const short8*)&Bs[(wn + ni * 16 + mr) * 40 + q8];
#pragma unroll
    for (int mi = 0; mi < 4; ++mi)
#pragma unroll
      for (int ni = 0; ni < 4; ++ni)
        acc[mi][ni] = __builtin_amdgcn_mfma_f32_16x16x32_bf16(af[mi], bv[ni], acc[mi][ni], 0, 0, 0);
  }
  // epilogue: C/D layout col=lane&15, row=q*4+r
  float* outf = (float*)outp;
  u16* outh = (u16*)outp;
#pragma unroll
  for (int mi = 0; mi < 4; ++mi)
#pragma unroll
    for (int r = 0; r < 4; ++r) {
      int row = m0 + wm + mi * 16 + q * 4 + r;
#pragma unroll
      for (int ni = 0; ni < 4; ++ni) {
        int col = n0 + wn + ni * 16 + mr;
        float v = acc[mi][ni][r];
        if (bias) v += bias[col];
        if (EPI == 1) v = fmaxf(v, 0.f);
        if (EPI == 2) v = 1.f / (1.f + __expf(-v));
        if (EPI == 3) v = 0.5f * v * (1.f + erff(v * 0.70710678118654752f));
        if (EPI == 5) v += res[(size_t)row * N + col];
        if (EPI == 2 || EPI == 4 || EPI == 5) outf[(size_t)row * N + col] = v;
        else                                  outh[(size_t)row * N + col] = f2b(v);
      }
    }
}

// ---------------- grid barrier: all-RELAXED atomics, explicit vmcnt ordering ----------------
__device__ __forceinline__ void grid_barrier() {
  __syncthreads();
  if (threadIdx.x == 0) {
    u32 g0 = __hip_atomic_load(&g_gen[0], __ATOMIC_RELAXED, __HIP_MEMORY_SCOPE_AGENT);
    asm volatile("" ::: "memory");
    int grp = blockIdx.x & (SNGRP - 1);
    u32 n = __hip_atomic_fetch_add(&g_cnt[grp * CPAD], 1u, __ATOMIC_RELAXED, __HIP_MEMORY_SCOPE_AGENT);
    bool done = false;
    if (n == SGRPSZ - 1) {
      u32 r = __hip_atomic_fetch_add(&g_root[0], 1u, __ATOMIC_RELAXED, __HIP_MEMORY_SCOPE_AGENT);
      if (r == SNGRP - 1) {
        for (int i = 0; i < SNGRP; ++i)
          __hip_atomic_store(&g_cnt[i * CPAD], 0u, __ATOMIC_RELAXED, __HIP_MEMORY_SCOPE_AGENT);
        __hip_atomic_store(&g_root[0], 0u, __ATOMIC_RELAXED, __HIP_MEMORY_SCOPE_AGENT);
        asm volatile("s_waitcnt vmcnt(0)" ::: "memory");  // resets visible before gen bump
        __hip_atomic_fetch_add(&g_gen[0], 1u, __ATOMIC_RELAXED, __HIP_MEMORY_SCOPE_AGENT);
        done = true;
      }
    }
    if (!done) {
      while (__hip_atomic_load(&g_gen[0], __ATOMIC_RELAXED, __HIP_MEMORY_SCOPE_AGENT) == g0)
        __builtin_amdgcn_s_sleep(1);
    }
    asm volatile("" ::: "memory");
  }
  __syncthreads();
}

// ---------------- persistent scan: h_t = z*sig(Wg h)+gamma*h+0.1*tanh(zWmi+Wmh h) ----------------
// 256 blocks: blk&127 -> 16-col slice, blk>>7 -> batch. h exchanged through L3 via
// RELAXED/AGENT atomics (cache-bypass) -- no cache-wide fence ops anywhere.
__global__ __launch_bounds__(256, 1)
void scan_kernel(const u16* __restrict__ WgT, const u16* __restrict__ WmhT,
                 const u16* __restrict__ zb, const float* __restrict__ gammab,
                 const float* __restrict__ zWmib, const float* __restrict__ bg,
                 const float* __restrict__ bm, float* __restrict__ Hst) {
  __shared__ float he[D_ / 2];        // h_prev even dims
  __shared__ float ho[D_ / 2];        // h_prev odd dims
  __shared__ float dotbuf[32];        // [cc]: cc<16 Wg dot, cc>=16 Wmh dot
  const int tid = threadIdx.x, wave = tid >> 6, lane = tid & 63;
  const int b = blockIdx.x >> 7;
  const int j0 = (blockIdx.x & 127) * 16;

  // weights in registers: wave w owns weight-cols cc = w*8..w*8+7 (cc<16 -> Wg col j0+cc, else Wmh)
  u32 w_reg[8][16];
#pragma unroll
  for (int c = 0; c < 8; ++c) {
    int cc = wave * 8 + c;
    const u16* Wt = (cc < 16 ? WgT : WmhT) + (size_t)(j0 + (cc & 15)) * D_;
#pragma unroll
    for (int i = 0; i < 16; ++i)
      w_reg[c][i] = *(const u32*)&Wt[i * 128 + lane * 2];
  }
  for (int i = tid; i < D_ / 2; i += 256) { he[i] = 0.f; ho[i] = 0.f; }

  const int jj = tid;                  // epilogue col index when tid<16
  float pbg = 0.f, pbm = 0.f;
  if (tid < 16) { pbg = bg[j0 + jj]; pbm = bm[j0 + jj]; }
  __syncthreads();

  for (int t = 0; t < S_; ++t) {
    // prefetch this step's elementwise operands (overlaps the matvec)
    size_t off = ((size_t)b * S_ + t) * D_ + j0 + jj;
    float pz = 0.f, pg = 0.f, pzw = 0.f;
    if (tid < 16) { pz = b2f(zb[off]); pg = gammab[off]; pzw = zWmib[off]; }

    float acc[8];
#pragma unroll
    for (int c = 0; c < 8; ++c) acc[c] = 0.f;
#pragma unroll
    for (int i = 0; i < 16; ++i) {
      float hx = he[i * 64 + lane];
      float hy = ho[i * 64 + lane];
#pragma unroll
      for (int c = 0; c < 8; ++c) {
        u32 w = w_reg[c][i];
        float w0 = b2f((u16)(w & 0xffff));
        float w1 = b2f((u16)(w >> 16));
        acc[c] += w0 * hx + w1 * hy;
      }
    }
#pragma unroll
    for (int c = 0; c < 8; ++c) {
      float v = acc[c];
      for (int o = 32; o >= 1; o >>= 1) v += __shfl_xor(v, o);
      if (lane == 0) dotbuf[wave * 8 + c] = v;
    }
    __syncthreads();
    if (tid < 16) {
      int j = j0 + jj;
      float gd = dotbuf[jj] + pbg;
      float md = dotbuf[16 + jj] + pbm;
      float gate = 1.f / (1.f + __expf(-gd));
      float hnew = tanhf(pzw + md);
      float hprev = (j & 1) ? ho[j >> 1] : he[j >> 1];
      float hv = pz * gate + pg * hprev + 0.1f * hnew;
      __hip_atomic_store(&Hst[off], hv, __ATOMIC_RELAXED, __HIP_MEMORY_SCOPE_AGENT);
    }
    asm volatile("s_waitcnt vmcnt(0)" ::: "memory");  // publish h before counter
    grid_barrier();
    {
      float* src = (float*)&Hst[((size_t)b * S_ + t) * D_];
      int base = tid * 8;
      float v[8];
#pragma unroll
      for (int u = 0; u < 8; ++u)
        v[u] = __hip_atomic_load(&src[base + u], __ATOMIC_RELAXED, __HIP_MEMORY_SCOPE_AGENT);
      int p = base >> 1;
      he[p] = v[0]; he[p + 1] = v[2]; he[p + 2] = v[4]; he[p + 3] = v[6];
      ho[p] = v[1]; ho[p + 1] = v[3]; ho[p + 2] = v[5]; ho[p + 3] = v[7];
    }
    __syncthreads();
  }
}

// ---------------- slot attention over bank (parallel over all t) ----------------
__global__ __launch_bounds__(256)
void attn_kernel(const u16* __restrict__ Q, const float* __restrict__ Hst,
                 u16* __restrict__ CTX) {
  __shared__ float qs[4][128];
  const int wave = threadIdx.x >> 6, lane = threadIdx.x & 63;
  const int task = blockIdx.x * 4 + wave;         // 16384 tasks
  const int h = task & 15;
  const int t = (task >> 4) & (S_ - 1);
  const int b = task >> 13;
  const int row = b * S_ + t;
  {
    u32 qv = *(const u32*)&Q[(size_t)row * D_ + h * 128 + lane * 2];
    qs[wave][lane * 2]     = b2f((u16)(qv & 0xffff));
    qs[wave][lane * 2 + 1] = b2f((u16)(qv >> 16));
  }
  __syncthreads();
  const int s = lane & 31, half = lane >> 5;
  int j = t - 1 - s;                 // the 32 most recent states; slot id = j%32 (unique)
  bool valid = (t > 0) && (j >= 0);
  float dot = 0.f;
  if (valid) {
    const float* Krow = Hst + ((size_t)b * S_ + j) * D_ + h * 128 + half * 64;
    const float* qp = &qs[wave][half * 64];
#pragma unroll
    for (int it = 0; it < 16; ++it) {
      float4 kv = *(const float4*)&Krow[it * 4];
      dot += qp[it*4] * kv.x + qp[it*4+1] * kv.y + qp[it*4+2] * kv.z + qp[it*4+3] * kv.w;
    }
  }
  dot += __shfl_xor(dot, 32);
  float score = valid ? dot * 0.08838834764831843f : 0.f;  // 1/sqrt(128); empty slot -> q.0=0
  float mx = score;
  for (int off = 16; off >= 1; off >>= 1) mx = fmaxf(mx, __shfl_xor(mx, off));
  float p = __expf(score - mx);
  float sum = p;
  for (int off = 16; off >= 1; off >>= 1) sum += __shfl_xor(sum, off);
  float aw = p / sum;
  // ctx: lane covers dims d0 = lane*2, d0+1
  float cx = 0.f, cy = 0.f;
  for (int ss = 0; ss < 32; ++ss) {
    float a = __shfl(aw, ss);
    int jj2 = t - 1 - ss;
    if (t > 0 && jj2 >= 0) {
      float2 kv = *(const float2*)&Hst[((size_t)b * S_ + jj2) * D_ + h * 128 + lane * 2];
      cx += a * kv.x; cy += a * kv.y;
    }
  }
  u32 o = (u32)f2b(cx) | ((u32)f2b(cy) << 16);
  *(u32*)&CTX[(size_t)row * D_ + h * 128 + lane * 2] = o;
}

// ---------------- combine: x_res = x + h + memctx + 0.1*v (f32 out) ----------------
__global__ __launch_bounds__(256)
void combine_k(const float* __restrict__ x, const u16* __restrict__ v,
               const float* __restrict__ Hs, const float* __restrict__ mc,
               float* __restrict__ xres) {
  size_t i = ((size_t)blockIdx.x * 256 + threadIdx.x) * 4;
  float4 xv = *(const float4*)&x[i];
  uint2 vv = *(const uint2*)&v[i];
  float4 hh = *(const float4*)&Hs[i];
  float4 m  = *(const float4*)&mc[i];
  float4 o;
  o.x = xv.x + hh.x + m.x + 0.1f * b2f((u16)(vv.x & 0xffff));
  o.y = xv.y + hh.y + m.y + 0.1f * b2f((u16)(vv.x >> 16));
  o.z = xv.z + hh.z + m.z + 0.1f * b2f((u16)(vv.y & 0xffff));
  o.w = xv.w + hh.w + m.w + 0.1f * b2f((u16)(vv.y >> 16));
  *(float4*)&xres[i] = o;
}

// ---------------- host ----------------
static void* sym(const void* s) { void* p = nullptr; (void)hipGetSymbolAddress(&p, s); return p; }

extern "C" void kernel_launch(void* const* d_in, const int* in_sizes, int n_in,
                              void* d_out, int out_size, void* d_ws, size_t ws_size,
                              hipStream_t stream) {
  (void)in_sizes; (void)n_in; (void)d_ws; (void)ws_size; (void)out_size;
  const float* x   = (const float*)d_in[0];
  const float* Wq  = (const float*)d_in[1];  const float* bq  = (const float*)d_in[2];
  const float* Wk  = (const float*)d_in[3];  const float* bk  = (const float*)d_in[4];
  const float* Wv  = (const float*)d_in[5];  const float* bv  = (const float*)d_in[6];
  const float* Wz  = (const float*)d_in[7];  const float* bz  = (const float*)d_in[8];
  const float* Wg  = (const float*)d_in[9];  const float* bg  = (const float*)d_in[10];
  const float* n1w = (const float*)d_in[11]; const float* n2w = (const float*)d_in[12];
  const float* Wd1 = (const float*)d_in[13]; const float* bd1 = (const float*)d_in[14];
  const float* Wd2 = (const float*)d_in[15]; const float* bd2 = (const float*)d_in[16];
  const float* Wmi = (const float*)d_in[17];
  const float* Wmh = (const float*)d_in[18]; const float* bm  = (const float*)d_in[19];
  const float* Wo  = (const float*)d_in[20]; const float* bo  = (const float*)d_in[21];
  const float* W1f = (const float*)d_in[22]; const float* b1f = (const float*)d_in[23];
  const float* W2f = (const float*)d_in[24]; const float* b2f_ = (const float*)d_in[25];

  u16* WqT  = (u16*)sym(HIP_SYMBOL(g_WqT));   u16* WkT  = (u16*)sym(HIP_SYMBOL(g_WkT));
  u16* WvT  = (u16*)sym(HIP_SYMBOL(g_WvT));   u16* WzT  = (u16*)sym(HIP_SYMBOL(g_WzT));
  u16* WgT  = (u16*)sym(HIP_SYMBOL(g_WgT));   u16* WmhT = (u16*)sym(HIP_SYMBOL(g_WmhT));
  u16* WmiT = (u16*)sym(HIP_SYMBOL(g_WmiT));  u16* WoT  = (u16*)sym(HIP_SYMBOL(g_WoT));
  u16* Wd1T = (u16*)sym(HIP_SYMBOL(g_Wd1T));  u16* Wd2T = (u16*)sym(HIP_SYMBOL(g_Wd2T));
  u16* W1fT = (u16*)sym(HIP_SYMBOL(g_W1fT));  u16* W2fT = (u16*)sym(HIP_SYMBOL(g_W2fT));
  u16* xn  = (u16*)sym(HIP_SYMBOL(g_xn));
  u16* qb  = (u16*)sym(HIP_SYMBOL(g_q));   u16* kb2 = (u16*)sym(HIP_SYMBOL(g_k));
  u16* vb  = (u16*)sym(HIP_SYMBOL(g_v));   u16* zb  = (u16*)sym(HIP_SYMBOL(g_z));
  u16* t1  = (u16*)sym(HIP_SYMBOL(g_t1));
  float* gamma  = (float*)sym(HIP_SYMBOL(g_gamma));
  float* zWmi   = (float*)sym(HIP_SYMBOL(g_zWmi));
  float* Hst    = (float*)sym(HIP_SYMBOL(g_H));
  float* memctx = (float*)sym(HIP_SYMBOL(g_memctx));
  float* xres   = (float*)sym(HIP_SYMBOL(g_xres));
  u16* ctx  = (u16*)sym(HIP_SYMBOL(g_ctx));
  u16* xrn  = (u16*)sym(HIP_SYMBOL(g_xrn));
  u16* ffn1 = (u16*)sym(HIP_SYMBOL(g_ffn1));

  // weight transposes + fp32->bf16 casts (every launch; idempotent)
  transpose_k<<<dim3(32, 32), 256, 0, stream>>>(Wq,  WqT,  D_, D_);
  transpose_k<<<dim3(32, 32), 256, 0, stream>>>(Wk,  WkT,  D_, D_);
  transpose_k<<<dim3(32, 32), 256, 0, stream>>>(Wv,  WvT,  D_, D_);
  transpose_k<<<dim3(32, 32), 256, 0, stream>>>(Wz,  WzT,  D_, D_);
  transpose_k<<<dim3(32, 32), 256, 0, stream>>>(Wg,  WgT,  D_, D_);
  transpose_k<<<dim3(32, 32), 256, 0, stream>>>(Wmh, WmhT, D_, D_);
  transpose_k<<<dim3(32, 32), 256, 0, stream>>>(Wmi, WmiT, D_, D_);
  transpose_k<<<dim3(32, 32), 256, 0, stream>>>(Wo,  WoT,  D_, D_);
  transpose_k<<<dim3(32, 8),  256, 0, stream>>>(Wd1, Wd1T, D_, INNER_);
  transpose_k<<<dim3(8, 32),  256, 0, stream>>>(Wd2, Wd2T, INNER_, D_);
  transpose_k<<<dim3(32, 128), 256, 0, stream>>>(W1f, W1fT, D_, FFN_);
  transpose_k<<<dim3(128, 32), 256, 0, stream>>>(W2f, W2fT, FFN_, D_);

  rmsnorm_k<<<NROW, 256, 0, stream>>>(x, n1w, xn);

  gemm_bt<0><<<dim3(8, 16), 256, 0, stream>>>(xn, WqT, bq, nullptr, qb,  NROW, D_, D_);
  gemm_bt<0><<<dim3(8, 16), 256, 0, stream>>>(xn, WkT, bk, nullptr, kb2, NROW, D_, D_);
  gemm_bt<0><<<dim3(8, 16), 256, 0, stream>>>(xn, WvT, bv, nullptr, vb,  NROW, D_, D_);
  gemm_bt<0><<<dim3(8, 16), 256, 0, stream>>>(xn, WzT, bz, nullptr, zb,  NROW, D_, D_);

  gemm_bt<1><<<dim3(8, 4),  256, 0, stream>>>(kb2, Wd1T, bd1, nullptr, t1,    NROW, INNER_, D_);
  gemm_bt<2><<<dim3(8, 16), 256, 0, stream>>>(t1,  Wd2T, bd2, nullptr, gamma, NROW, D_, INNER_);
  gemm_bt<4><<<dim3(8, 16), 256, 0, stream>>>(zb,  WmiT, nullptr, nullptr, zWmi, NROW, D_, D_);

  scan_kernel<<<SNBLK, 256, 0, stream>>>(WgT, WmhT, zb, gamma, zWmi, bg, bm, Hst);

  attn_kernel<<<4096, 256, 0, stream>>>(qb, Hst, ctx);
  gemm_bt<4><<<dim3(8, 16), 256, 0, stream>>>(ctx, WoT, bo, nullptr, memctx, NROW, D_, D_);
  combine_k<<<2048, 256, 0, stream>>>(x, vb, Hst, memctx, xres);

  rmsnorm_k<<<NROW, 256, 0, stream>>>(xres, n2w, xrn);
  gemm_bt<3><<<dim3(8, 64), 256, 0, stream>>>(xrn,  W1fT, b1f, nullptr, ffn1, NROW, FFN_, D_);
  gemm_bt<5><<<dim3(8, 16), 256, 0, stream>>>(ffn1, W2fT, b2f_, xres, (float*)d_out, NROW, D_, FFN_);
}